// Round 7
// baseline (1047.260 us; speedup 1.0000x reference)
//
#include <hip/hip_runtime.h>
#include <cstdint>
#include <cstddef>

// Graph U-Net (no pooling), N=8192, D=256, L=3.
// R11: MEASUREMENT PROBE. Exact R5 pipeline (703.1 us verified), every
// kernel launched TWICE (all kernels are idempotent: pure functions of
// inputs that are stable at their launch point; k_build's atomic order only
// permutes col-list order, which is fp-order-insensitive within threshold).
//   compute_total ~= dur(R11) - dur(R5)      [warm lower bound]
//   per-iter overhead ~= 2*dur(R5) - dur(R11)
// This decides whether further kernel optimization can help at all, and if
// so which kernel gets the next round.

#define GN 8192
#define GD 256
#define CAP 320   // max degree capacity; max observed degree ~175

typedef unsigned int uint32;
using frag_ab = __attribute__((ext_vector_type(8))) short;   // 8 bf16
using frag_cd = __attribute__((ext_vector_type(4))) float;   // 4 fp32

// RNE float -> bf16 bits (values are finite; NaN path not needed)
static __device__ inline unsigned short f2bf(float x) {
    uint32 u = __float_as_uint(x);
    u += 0x7fffu + ((u >> 16) & 1u);
    return (unsigned short)(u >> 16);
}

// ---------------------------------------------------------------------------
// Kernel 1: build adjacency lists + dinv. One block per row.
__global__ __launch_bounds__(256) void k_build(const float* __restrict__ g,
                                               unsigned short* __restrict__ col,
                                               int* __restrict__ cnt,
                                               float* __restrict__ dinv)
{
    __shared__ int s_cnt;
    const int i = blockIdx.x;
    const int tid = threadIdx.x;
    if (tid == 0) s_cnt = 0;
    __syncthreads();
    const float4* grow = (const float4*)(g + (size_t)i * GN);
    unsigned short* crow = col + (size_t)i * CAP;
    for (int j4 = tid; j4 < GN / 4; j4 += 256) {
        float4 v = grow[j4];
        int j = j4 * 4;
        if (v.x != 0.0f) { int p = atomicAdd(&s_cnt, 1); if (p < CAP) crow[p] = (unsigned short)(j + 0); }
        if (v.y != 0.0f) { int p = atomicAdd(&s_cnt, 1); if (p < CAP) crow[p] = (unsigned short)(j + 1); }
        if (v.z != 0.0f) { int p = atomicAdd(&s_cnt, 1); if (p < CAP) crow[p] = (unsigned short)(j + 2); }
        if (v.w != 0.0f) { int p = atomicAdd(&s_cnt, 1); if (p < CAP) crow[p] = (unsigned short)(j + 3); }
    }
    __syncthreads();
    if (tid == 0) {
        int n = s_cnt; if (n > CAP) n = CAP;
        cnt[i] = n;
        dinv[i] = rsqrtf((float)s_cnt + 1.0f);
    }
}

// ---------------------------------------------------------------------------
// Kernel 2: hs_bf = bf16(dinv[:,None] * h)
__global__ __launch_bounds__(256) void k_scale(const float* __restrict__ h,
                                               const float* __restrict__ dinv,
                                               unsigned short* __restrict__ hs_bf)
{
    int idx = blockIdx.x * 256 + threadIdx.x;      // float4 index
    float4 v = ((const float4*)h)[idx];
    int row = idx / (GD / 4);
    float dv = dinv[row];
    ushort4 r;
    r.x = f2bf(v.x * dv); r.y = f2bf(v.y * dv);
    r.z = f2bf(v.z * dv); r.w = f2bf(v.w * dv);
    ((ushort4*)hs_bf)[idx] = r;
}

// ---------------------------------------------------------------------------
// Kernel 2b: generic fp32 -> bf16 convert (weights), n multiple of 1024
__global__ __launch_bounds__(256) void k_f2bf(const float* __restrict__ src,
                                              unsigned short* __restrict__ dst)
{
    int idx = blockIdx.x * 256 + threadIdx.x;      // float4 index
    float4 v = ((const float4*)src)[idx];
    ushort4 r;
    r.x = f2bf(v.x); r.y = f2bf(v.y); r.z = f2bf(v.z); r.w = f2bf(v.w);
    ((ushort4*)dst)[idx] = r;
}

// ---------------------------------------------------------------------------
// Kernel 3: SpMM (R5 version: 1-D grid 4096, XCD-chunked, 32-bit addressing,
// unroll 8, split accumulators).
__global__ __launch_bounds__(256) void k_spmm(const uint32* __restrict__ hsw,
                                              const unsigned short* __restrict__ col,
                                              const int* __restrict__ cnt,
                                              const float* __restrict__ dinv,
                                              uint32* __restrict__ yw)
{
    __shared__ unsigned short s_cols[4][CAP];
    const int tid  = threadIdx.x;
    const int lr   = tid >> 6;          // wave id = local row 0..3
    const int lane = tid & 63;
    const int id   = blockIdx.x;        // 0..4095
    const int xcd7 = id & 7;
    const int chunk = xcd7 >> 2;        // XCDs 0-3 -> cols [0,64); 4-7 -> [64,128)
    const int xi    = (id >> 3) * 4 + (xcd7 & 3);   // 0..2047, bijective per chunk
    const int i     = xi * 4 + lr;
    const uint32 base = (uint32)(chunk * 64 + lane);   // uint col index (row stride 128)
    const int n = cnt[i];
    unsigned short* sc = s_cols[lr];
    for (int t = lane; t < n; t += 64) sc[t] = col[(size_t)i * CAP + t];
    // wave-coherent staging: producer == consumer wave; no barrier.

    float alo0 = 0.f, ahi0 = 0.f, alo1 = 0.f, ahi1 = 0.f;
    int t = 0;
    for (; t + 8 <= n; t += 8) {
        uint32 u[8];
#pragma unroll
        for (int k = 0; k < 8; ++k) {
            uint32 off = (uint32)sc[t + k] * 128u + base;
            u[k] = hsw[off];
        }
#pragma unroll
        for (int k = 0; k < 8; k += 2) {
            alo0 += __uint_as_float(u[k]     << 16);
            ahi0 += __uint_as_float(u[k]     & 0xffff0000u);
            alo1 += __uint_as_float(u[k + 1] << 16);
            ahi1 += __uint_as_float(u[k + 1] & 0xffff0000u);
        }
    }
    for (; t < n; ++t) {
        uint32 u = hsw[(uint32)sc[t] * 128u + base];
        alo0 += __uint_as_float(u << 16);
        ahi0 += __uint_as_float(u & 0xffff0000u);
    }
    uint32 us = hsw[(uint32)i * 128u + base];   // self-loop (+I)
    float alo = alo0 + alo1 + __uint_as_float(us << 16);
    float ahi = ahi0 + ahi1 + __uint_as_float(us & 0xffff0000u);
    const float dv = dinv[i];
    alo *= dv; ahi *= dv;
    yw[(uint32)i * 128u + base] = (uint32)f2bf(alo) | ((uint32)f2bf(ahi) << 16);
}

// ---------------------------------------------------------------------------
// Kernel 4: MFMA bf16 linear layer (R4/R5 version).
__global__ __launch_bounds__(256) void k_gemm(const unsigned short* __restrict__ Y,
                                              const unsigned short* __restrict__ W,
                                              const float* __restrict__ bias,
                                              const float* __restrict__ dinv,
                                              const float* __restrict__ skip,
                                              float* __restrict__ h_out,
                                              unsigned short* __restrict__ hs_out,
                                              float* __restrict__ sum_out,
                                              const float* __restrict__ add_src)
{
    const int tid  = threadIdx.x;
    const int w    = tid >> 6;         // wave 0..3
    const int lane = tid & 63;
    const int quad = lane >> 4;
    const int l16  = lane & 15;
    const int m0 = blockIdx.x * 64 + w * 16;   // wave's 16 rows
    const int n0 = blockIdx.y * 64;            // block's 64 cols

    frag_cd acc0 = {0.f,0.f,0.f,0.f}, acc1 = {0.f,0.f,0.f,0.f};
    frag_cd acc2 = {0.f,0.f,0.f,0.f}, acc3 = {0.f,0.f,0.f,0.f};

    const size_t abase  = (size_t)(m0 + l16) * GD + quad * 8;
    const size_t bbase0 = (size_t)(n0 +  0 + l16) * GD + quad * 8;
    const size_t bbase1 = (size_t)(n0 + 16 + l16) * GD + quad * 8;
    const size_t bbase2 = (size_t)(n0 + 32 + l16) * GD + quad * 8;
    const size_t bbase3 = (size_t)(n0 + 48 + l16) * GD + quad * 8;

#pragma unroll
    for (int k0 = 0; k0 < GD; k0 += 32) {
        frag_ab a  = *(const frag_ab*)(Y + abase  + k0);
        frag_ab b0 = *(const frag_ab*)(W + bbase0 + k0);
        frag_ab b1 = *(const frag_ab*)(W + bbase1 + k0);
        frag_ab b2 = *(const frag_ab*)(W + bbase2 + k0);
        frag_ab b3 = *(const frag_ab*)(W + bbase3 + k0);
        acc0 = __builtin_amdgcn_mfma_f32_16x16x32_bf16(a, b0, acc0, 0, 0, 0);
        acc1 = __builtin_amdgcn_mfma_f32_16x16x32_bf16(a, b1, acc1, 0, 0, 0);
        acc2 = __builtin_amdgcn_mfma_f32_16x16x32_bf16(a, b2, acc2, 0, 0, 0);
        acc3 = __builtin_amdgcn_mfma_f32_16x16x32_bf16(a, b3, acc3, 0, 0, 0);
    }

    const float bn0 = bias[n0 +  0 + l16];
    const float bn1 = bias[n0 + 16 + l16];
    const float bn2 = bias[n0 + 32 + l16];
    const float bn3 = bias[n0 + 48 + l16];

#pragma unroll
    for (int reg = 0; reg < 4; ++reg) {
        const int m = m0 + quad * 4 + reg;
        const float dv = dinv[m];
        float v[4];
        v[0] = fmaxf(acc0[reg] + bn0, 0.f);
        v[1] = fmaxf(acc1[reg] + bn1, 0.f);
        v[2] = fmaxf(acc2[reg] + bn2, 0.f);
        v[3] = fmaxf(acc3[reg] + bn3, 0.f);
#pragma unroll
        for (int nt = 0; nt < 4; ++nt) {
            const size_t idx = (size_t)m * GD + n0 + nt * 16 + l16;
            const float x = v[nt];
            if (h_out)  h_out[idx] = x;
            if (hs_out) {
                float s = skip ? skip[idx] : 0.f;
                hs_out[idx] = f2bf(dv * (x + s));
            }
            if (sum_out) sum_out[idx] = x + add_src[idx];
        }
    }
}

// ---------------------------------------------------------------------------
extern "C" void kernel_launch(void* const* d_in, const int* in_sizes, int n_in,
                              void* d_out, int out_size, void* d_ws, size_t ws_size,
                              hipStream_t stream)
{
    const float* g  = (const float*)d_in[0];
    const float* h  = (const float*)d_in[1];
    const float* Wd = (const float*)d_in[2];
    const float* bd = (const float*)d_in[3];
    const float* Wb = (const float*)d_in[4];
    const float* bb = (const float*)d_in[5];
    const float* Wu = (const float*)d_in[6];
    const float* bu = (const float*)d_in[7];
    float* out = (float*)d_out;

    char* ws = (char*)d_ws;
    float*          dinv = (float*)ws;                               // 32 KB
    int*            cnt  = (int*)(ws + 32 * 1024);                   // 32 KB
    unsigned short* col  = (unsigned short*)(ws + 64 * 1024);        // 5.24 MB
    size_t off = 64 * 1024 + (size_t)GN * CAP * sizeof(unsigned short);
    off = (off + 255) & ~(size_t)255;
    unsigned short* hs_bf = (unsigned short*)(ws + off); off += (size_t)GN * GD * 2;  // 4 MB
    unsigned short* y_bf  = (unsigned short*)(ws + off); off += (size_t)GN * GD * 2;  // 4 MB
    unsigned short* w_bf  = (unsigned short*)(ws + off); off += (size_t)7 * GD * GD * 2; // 0.9 MB
    off = (off + 255) & ~(size_t)255;
    float* dbuf1 = (float*)(ws + off); off += (size_t)GN * GD * 4;   // 8 MB
    float* dbuf2 = (float*)(ws + off); off += (size_t)GN * GD * 4;   // 8 MB
    float* dbuf3 = (float*)(ws + off); off += (size_t)GN * GD * 4;   // 8 MB
    (void)ws_size; (void)in_sizes; (void)n_in; (void)out_size;

    const size_t ND = (size_t)GN * GD;
    const int WSZ = GD * GD;   // 65536 elements per weight matrix
    dim3 ggrid(GN / 64, GD / 64);

    // Every launch duplicated (idempotent) — timing decomposition probe.
#define DUP2(call) do { call; call; } while (0)

    DUP2((k_build<<<GN, 256, 0, stream>>>(g, col, cnt, dinv)));
    DUP2((k_scale<<<GN * GD / 4 / 256, 256, 0, stream>>>(h, dinv, hs_bf)));
    DUP2((k_f2bf<<<3 * WSZ / 4 / 256, 256, 0, stream>>>(Wd, w_bf + 0 * (size_t)WSZ)));
    DUP2((k_f2bf<<<1 * WSZ / 4 / 256, 256, 0, stream>>>(Wb, w_bf + 3 * (size_t)WSZ)));
    DUP2((k_f2bf<<<3 * WSZ / 4 / 256, 256, 0, stream>>>(Wu, w_bf + 4 * (size_t)WSZ)));

    // down 0..2
    DUP2((k_spmm<<<4096, 256, 0, stream>>>((const uint32*)hs_bf, col, cnt, dinv, (uint32*)y_bf)));
    DUP2((k_gemm<<<ggrid, 256, 0, stream>>>(y_bf, w_bf + 0 * (size_t)WSZ, bd + 0 * GD, dinv, nullptr, dbuf1, hs_bf, nullptr, nullptr)));
    DUP2((k_spmm<<<4096, 256, 0, stream>>>((const uint32*)hs_bf, col, cnt, dinv, (uint32*)y_bf)));
    DUP2((k_gemm<<<ggrid, 256, 0, stream>>>(y_bf, w_bf + 1 * (size_t)WSZ, bd + 1 * GD, dinv, nullptr, dbuf2, hs_bf, nullptr, nullptr)));
    DUP2((k_spmm<<<4096, 256, 0, stream>>>((const uint32*)hs_bf, col, cnt, dinv, (uint32*)y_bf)));
    DUP2((k_gemm<<<ggrid, 256, 0, stream>>>(y_bf, w_bf + 2 * (size_t)WSZ, bd + 2 * GD, dinv, nullptr, dbuf3, hs_bf, nullptr, nullptr)));

    // bottom
    DUP2((k_spmm<<<4096, 256, 0, stream>>>((const uint32*)hs_bf, col, cnt, dinv, (uint32*)y_bf)));
    DUP2((k_gemm<<<ggrid, 256, 0, stream>>>(y_bf, w_bf + 3 * (size_t)WSZ, bb, dinv, dbuf3, nullptr, hs_bf, nullptr, nullptr)));

    // up 0
    DUP2((k_spmm<<<4096, 256, 0, stream>>>((const uint32*)hs_bf, col, cnt, dinv, (uint32*)y_bf)));
    DUP2((k_gemm<<<ggrid, 256, 0, stream>>>(y_bf, w_bf + 4 * (size_t)WSZ, bu + 0 * GD, dinv, dbuf2, out + 0 * ND, hs_bf, nullptr, nullptr)));
    // up 1
    DUP2((k_spmm<<<4096, 256, 0, stream>>>((const uint32*)hs_bf, col, cnt, dinv, (uint32*)y_bf)));
    DUP2((k_gemm<<<ggrid, 256, 0, stream>>>(y_bf, w_bf + 5 * (size_t)WSZ, bu + 1 * GD, dinv, dbuf1, out + 1 * ND, hs_bf, nullptr, nullptr)));
    // up 2
    DUP2((k_spmm<<<4096, 256, 0, stream>>>((const uint32*)hs_bf, col, cnt, dinv, (uint32*)y_bf)));
    DUP2((k_gemm<<<ggrid, 256, 0, stream>>>(y_bf, w_bf + 6 * (size_t)WSZ, bu + 2 * GD, dinv, nullptr, out + 2 * ND, nullptr, out + 3 * ND, h)));
#undef DUP2
}

// Round 8
// 747.833 us; speedup vs baseline: 1.4004x; 1.4004x over previous
//
#include <hip/hip_runtime.h>
#include <cstdint>
#include <cstddef>

// Graph U-Net (no pooling), N=8192, D=256, L=3.
// R12 = R5 base + three surgical changes, informed by the R11 probe
// (fixed harness cost F~359us; kernel budget ~344us; spmm is the headroom):
//   (1) k_spmm: uint2 full-row gathers (R7's proven-correct arithmetic),
//       ZERO nontemporal hints (R7's regression was the nt hints: nt y-stores
//       forced gemm to read y from HBM; nt dbuf stores forced skip re-reads
//       from HBM; nt col loads refetched 5MB x7). 30% fewer issue slots per
//       neighbor: 1 dwordx2 + 1/4 ds_read_b64 vs 2x(dword + ds_read_u16).
//   (2) ushort4 LDS col readback (1 ds_read per 4 neighbors).
//   (3) k_prep merges scale + 3 weight converts (R9's proven kernel):
//       19 -> 16 launches.
// k_build and k_gemm byte-identical to R5 (703.1us verified).

#define GN 8192
#define GD 256
#define CAP 320   // max degree capacity; max observed degree ~175

typedef unsigned int uint32;
using frag_ab = __attribute__((ext_vector_type(8))) short;   // 8 bf16
using frag_cd = __attribute__((ext_vector_type(4))) float;   // 4 fp32
using u32x2   = __attribute__((ext_vector_type(2))) uint32;  // 8B gather unit

// RNE float -> bf16 bits (values are finite; NaN path not needed)
static __device__ inline unsigned short f2bf(float x) {
    uint32 u = __float_as_uint(x);
    u += 0x7fffu + ((u >> 16) & 1u);
    return (unsigned short)(u >> 16);
}

// ---------------------------------------------------------------------------
// Kernel 1: build adjacency lists + dinv. One block per row. (R5 version)
__global__ __launch_bounds__(256) void k_build(const float* __restrict__ g,
                                               unsigned short* __restrict__ col,
                                               int* __restrict__ cnt,
                                               float* __restrict__ dinv)
{
    __shared__ int s_cnt;
    const int i = blockIdx.x;
    const int tid = threadIdx.x;
    if (tid == 0) s_cnt = 0;
    __syncthreads();
    const float4* grow = (const float4*)(g + (size_t)i * GN);
    unsigned short* crow = col + (size_t)i * CAP;
    for (int j4 = tid; j4 < GN / 4; j4 += 256) {
        float4 v = grow[j4];
        int j = j4 * 4;
        if (v.x != 0.0f) { int p = atomicAdd(&s_cnt, 1); if (p < CAP) crow[p] = (unsigned short)(j + 0); }
        if (v.y != 0.0f) { int p = atomicAdd(&s_cnt, 1); if (p < CAP) crow[p] = (unsigned short)(j + 1); }
        if (v.z != 0.0f) { int p = atomicAdd(&s_cnt, 1); if (p < CAP) crow[p] = (unsigned short)(j + 2); }
        if (v.w != 0.0f) { int p = atomicAdd(&s_cnt, 1); if (p < CAP) crow[p] = (unsigned short)(j + 3); }
    }
    __syncthreads();
    if (tid == 0) {
        int n = s_cnt; if (n > CAP) n = CAP;
        cnt[i] = n;
        dinv[i] = rsqrtf((float)s_cnt + 1.0f);
    }
}

// ---------------------------------------------------------------------------
// Kernel 2: fused preprocessing (R9's proven kernel).
//   blocks [0,2048):     hs = bf16(dinv[:,None] * h)
//   blocks [2048,2240):  w_bf[0..3W)  = bf16(Wd)
//   blocks [2240,2304):  w_bf[3W..4W) = bf16(Wb)
//   blocks [2304,2496):  w_bf[4W..7W) = bf16(Wu)
__global__ __launch_bounds__(256) void k_prep(const float* __restrict__ h,
                                              const float* __restrict__ dinv,
                                              unsigned short* __restrict__ hs,
                                              const float* __restrict__ Wd,
                                              const float* __restrict__ Wb,
                                              const float* __restrict__ Wu,
                                              unsigned short* __restrict__ w_bf)
{
    const int WSZ = GD * GD;
    int bid = blockIdx.x;
    if (bid < 2048) {
        int idx = bid * 256 + threadIdx.x;      // float4 index
        float4 v = ((const float4*)h)[idx];
        int row = idx >> 6;                     // / (GD/4)
        float dv = dinv[row];
        ushort4 r;
        r.x = f2bf(v.x * dv); r.y = f2bf(v.y * dv);
        r.z = f2bf(v.z * dv); r.w = f2bf(v.w * dv);
        ((ushort4*)hs)[idx] = r;
        return;
    }
    bid -= 2048;
    const float* src;
    unsigned short* dst;
    if (bid < 192)      { src = Wd + (size_t)bid * 1024;         dst = w_bf + (size_t)bid * 1024; }
    else if (bid < 256) { src = Wb + (size_t)(bid - 192) * 1024; dst = w_bf + 3 * (size_t)WSZ + (size_t)(bid - 192) * 1024; }
    else                { src = Wu + (size_t)(bid - 256) * 1024; dst = w_bf + 4 * (size_t)WSZ + (size_t)(bid - 256) * 1024; }
    int t = threadIdx.x;
    float4 v = ((const float4*)src)[t];
    ushort4 r;
    r.x = f2bf(v.x); r.y = f2bf(v.y); r.z = f2bf(v.z); r.w = f2bf(v.w);
    ((ushort4*)dst)[t] = r;
}

// ---------------------------------------------------------------------------
// Kernel 3: SpMM. y_bf[i,:] = bf16(dinv[i]*(hs[i,:] + sum_n hs[n,:]))
// One wave per row; lane owns 8 B (4 bf16, elems 4l..4l+3). Per neighbor:
// 1 global_load_dwordx2 (wave = 512 B contiguous = full row), 8 VALU
// unpack-adds, 1/4 ds_read_b64 (ushort4 col readback). No nt hints anywhere.
// 2048 blocks -> 32 waves/CU.
__global__ __launch_bounds__(256) void k_spmm(const u32x2* __restrict__ hsw,
                                              const unsigned short* __restrict__ col,
                                              const int* __restrict__ cnt,
                                              const float* __restrict__ dinv,
                                              u32x2* __restrict__ yw)
{
    __shared__ unsigned short s_cols[4][CAP];
    const int tid  = threadIdx.x;
    const int lr   = tid >> 6;          // wave id = local row 0..3
    const int lane = tid & 63;
    const int i    = blockIdx.x * 4 + lr;
    const int n    = cnt[i];
    unsigned short* sc = s_cols[lr];
    const unsigned short* crow = col + (size_t)i * CAP;
    for (int t = lane; t < n; t += 64) sc[t] = crow[t];
    // wave-coherent staging: producer == consumer wave; no barrier.

    float e0a = 0.f, e1a = 0.f, e2a = 0.f, e3a = 0.f;
    float e0b = 0.f, e1b = 0.f, e2b = 0.f, e3b = 0.f;
    int t = 0;
    for (; t + 8 <= n; t += 8) {
        ushort4 ca = *(const ushort4*)(sc + t);
        ushort4 cb = *(const ushort4*)(sc + t + 4);
        u32x2 u0 = hsw[(uint32)ca.x * 64u + lane];
        u32x2 u1 = hsw[(uint32)ca.y * 64u + lane];
        u32x2 u2 = hsw[(uint32)ca.z * 64u + lane];
        u32x2 u3 = hsw[(uint32)ca.w * 64u + lane];
        u32x2 u4 = hsw[(uint32)cb.x * 64u + lane];
        u32x2 u5 = hsw[(uint32)cb.y * 64u + lane];
        u32x2 u6 = hsw[(uint32)cb.z * 64u + lane];
        u32x2 u7 = hsw[(uint32)cb.w * 64u + lane];
        e0a += __uint_as_float(u0[0] << 16); e1a += __uint_as_float(u0[0] & 0xffff0000u);
        e2a += __uint_as_float(u0[1] << 16); e3a += __uint_as_float(u0[1] & 0xffff0000u);
        e0b += __uint_as_float(u1[0] << 16); e1b += __uint_as_float(u1[0] & 0xffff0000u);
        e2b += __uint_as_float(u1[1] << 16); e3b += __uint_as_float(u1[1] & 0xffff0000u);
        e0a += __uint_as_float(u2[0] << 16); e1a += __uint_as_float(u2[0] & 0xffff0000u);
        e2a += __uint_as_float(u2[1] << 16); e3a += __uint_as_float(u2[1] & 0xffff0000u);
        e0b += __uint_as_float(u3[0] << 16); e1b += __uint_as_float(u3[0] & 0xffff0000u);
        e2b += __uint_as_float(u3[1] << 16); e3b += __uint_as_float(u3[1] & 0xffff0000u);
        e0a += __uint_as_float(u4[0] << 16); e1a += __uint_as_float(u4[0] & 0xffff0000u);
        e2a += __uint_as_float(u4[1] << 16); e3a += __uint_as_float(u4[1] & 0xffff0000u);
        e0b += __uint_as_float(u5[0] << 16); e1b += __uint_as_float(u5[0] & 0xffff0000u);
        e2b += __uint_as_float(u5[1] << 16); e3b += __uint_as_float(u5[1] & 0xffff0000u);
        e0a += __uint_as_float(u6[0] << 16); e1a += __uint_as_float(u6[0] & 0xffff0000u);
        e2a += __uint_as_float(u6[1] << 16); e3a += __uint_as_float(u6[1] & 0xffff0000u);
        e0b += __uint_as_float(u7[0] << 16); e1b += __uint_as_float(u7[0] & 0xffff0000u);
        e2b += __uint_as_float(u7[1] << 16); e3b += __uint_as_float(u7[1] & 0xffff0000u);
    }
    for (; t < n; ++t) {
        u32x2 u = hsw[(uint32)sc[t] * 64u + lane];
        e0a += __uint_as_float(u[0] << 16); e1a += __uint_as_float(u[0] & 0xffff0000u);
        e2a += __uint_as_float(u[1] << 16); e3a += __uint_as_float(u[1] & 0xffff0000u);
    }
    u32x2 us = hsw[(uint32)i * 64u + lane];   // self-loop (+I)
    e0b += __uint_as_float(us[0] << 16); e1b += __uint_as_float(us[0] & 0xffff0000u);
    e2b += __uint_as_float(us[1] << 16); e3b += __uint_as_float(us[1] & 0xffff0000u);

    const float dv = dinv[i];
    const float e0 = (e0a + e0b) * dv;
    const float e1 = (e1a + e1b) * dv;
    const float e2 = (e2a + e2b) * dv;
    const float e3 = (e3a + e3b) * dv;
    u32x2 r;
    r[0] = (uint32)f2bf(e0) | ((uint32)f2bf(e1) << 16);
    r[1] = (uint32)f2bf(e2) | ((uint32)f2bf(e3) << 16);
    yw[(uint32)i * 64u + lane] = r;
}

// ---------------------------------------------------------------------------
// Kernel 4: MFMA bf16 linear layer (R5 version, no nt).
__global__ __launch_bounds__(256) void k_gemm(const unsigned short* __restrict__ Y,
                                              const unsigned short* __restrict__ W,
                                              const float* __restrict__ bias,
                                              const float* __restrict__ dinv,
                                              const float* __restrict__ skip,
                                              float* __restrict__ h_out,
                                              unsigned short* __restrict__ hs_out,
                                              float* __restrict__ sum_out,
                                              const float* __restrict__ add_src)
{
    const int tid  = threadIdx.x;
    const int w    = tid >> 6;         // wave 0..3
    const int lane = tid & 63;
    const int quad = lane >> 4;
    const int l16  = lane & 15;
    const int m0 = blockIdx.x * 64 + w * 16;   // wave's 16 rows
    const int n0 = blockIdx.y * 64;            // block's 64 cols

    frag_cd acc0 = {0.f,0.f,0.f,0.f}, acc1 = {0.f,0.f,0.f,0.f};
    frag_cd acc2 = {0.f,0.f,0.f,0.f}, acc3 = {0.f,0.f,0.f,0.f};

    const size_t abase  = (size_t)(m0 + l16) * GD + quad * 8;
    const size_t bbase0 = (size_t)(n0 +  0 + l16) * GD + quad * 8;
    const size_t bbase1 = (size_t)(n0 + 16 + l16) * GD + quad * 8;
    const size_t bbase2 = (size_t)(n0 + 32 + l16) * GD + quad * 8;
    const size_t bbase3 = (size_t)(n0 + 48 + l16) * GD + quad * 8;

#pragma unroll
    for (int k0 = 0; k0 < GD; k0 += 32) {
        frag_ab a  = *(const frag_ab*)(Y + abase  + k0);
        frag_ab b0 = *(const frag_ab*)(W + bbase0 + k0);
        frag_ab b1 = *(const frag_ab*)(W + bbase1 + k0);
        frag_ab b2 = *(const frag_ab*)(W + bbase2 + k0);
        frag_ab b3 = *(const frag_ab*)(W + bbase3 + k0);
        acc0 = __builtin_amdgcn_mfma_f32_16x16x32_bf16(a, b0, acc0, 0, 0, 0);
        acc1 = __builtin_amdgcn_mfma_f32_16x16x32_bf16(a, b1, acc1, 0, 0, 0);
        acc2 = __builtin_amdgcn_mfma_f32_16x16x32_bf16(a, b2, acc2, 0, 0, 0);
        acc3 = __builtin_amdgcn_mfma_f32_16x16x32_bf16(a, b3, acc3, 0, 0, 0);
    }

    const float bn0 = bias[n0 +  0 + l16];
    const float bn1 = bias[n0 + 16 + l16];
    const float bn2 = bias[n0 + 32 + l16];
    const float bn3 = bias[n0 + 48 + l16];

#pragma unroll
    for (int reg = 0; reg < 4; ++reg) {
        const int m = m0 + quad * 4 + reg;
        const float dv = dinv[m];
        float v[4];
        v[0] = fmaxf(acc0[reg] + bn0, 0.f);
        v[1] = fmaxf(acc1[reg] + bn1, 0.f);
        v[2] = fmaxf(acc2[reg] + bn2, 0.f);
        v[3] = fmaxf(acc3[reg] + bn3, 0.f);
#pragma unroll
        for (int nt = 0; nt < 4; ++nt) {
            const size_t idx = (size_t)m * GD + n0 + nt * 16 + l16;
            const float x = v[nt];
            if (h_out)  h_out[idx] = x;
            if (hs_out) {
                float s = skip ? skip[idx] : 0.f;
                hs_out[idx] = f2bf(dv * (x + s));
            }
            if (sum_out) sum_out[idx] = x + add_src[idx];
        }
    }
}

// ---------------------------------------------------------------------------
extern "C" void kernel_launch(void* const* d_in, const int* in_sizes, int n_in,
                              void* d_out, int out_size, void* d_ws, size_t ws_size,
                              hipStream_t stream)
{
    const float* g  = (const float*)d_in[0];
    const float* h  = (const float*)d_in[1];
    const float* Wd = (const float*)d_in[2];
    const float* bd = (const float*)d_in[3];
    const float* Wb = (const float*)d_in[4];
    const float* bb = (const float*)d_in[5];
    const float* Wu = (const float*)d_in[6];
    const float* bu = (const float*)d_in[7];
    float* out = (float*)d_out;

    char* ws = (char*)d_ws;
    float*          dinv = (float*)ws;                               // 32 KB
    int*            cnt  = (int*)(ws + 32 * 1024);                   // 32 KB
    unsigned short* col  = (unsigned short*)(ws + 64 * 1024);        // 5.24 MB
    size_t off = 64 * 1024 + (size_t)GN * CAP * sizeof(unsigned short);
    off = (off + 255) & ~(size_t)255;
    unsigned short* hs_bf = (unsigned short*)(ws + off); off += (size_t)GN * GD * 2;  // 4 MB
    unsigned short* y_bf  = (unsigned short*)(ws + off); off += (size_t)GN * GD * 2;  // 4 MB
    unsigned short* w_bf  = (unsigned short*)(ws + off); off += (size_t)7 * GD * GD * 2; // 0.9 MB
    off = (off + 255) & ~(size_t)255;
    float* dbuf1 = (float*)(ws + off); off += (size_t)GN * GD * 4;   // 8 MB
    float* dbuf2 = (float*)(ws + off); off += (size_t)GN * GD * 4;   // 8 MB
    float* dbuf3 = (float*)(ws + off); off += (size_t)GN * GD * 4;   // 8 MB
    (void)ws_size; (void)in_sizes; (void)n_in; (void)out_size;

    const size_t ND = (size_t)GN * GD;
    const int WSZ = GD * GD;   // 65536 elements per weight matrix
    dim3 ggrid(GN / 64, GD / 64);

    k_build<<<GN, 256, 0, stream>>>(g, col, cnt, dinv);
    k_prep<<<2496, 256, 0, stream>>>(h, dinv, hs_bf, Wd, Wb, Wu, w_bf);

    // down 0..2: h_out -> dbuf, hs_out -> hs_bf (no skip)
    k_spmm<<<GN / 4, 256, 0, stream>>>((const u32x2*)hs_bf, col, cnt, dinv, (u32x2*)y_bf);
    k_gemm<<<ggrid, 256, 0, stream>>>(y_bf, w_bf + 0 * (size_t)WSZ, bd + 0 * GD, dinv, nullptr, dbuf1, hs_bf, nullptr, nullptr);
    k_spmm<<<GN / 4, 256, 0, stream>>>((const u32x2*)hs_bf, col, cnt, dinv, (u32x2*)y_bf);
    k_gemm<<<ggrid, 256, 0, stream>>>(y_bf, w_bf + 1 * (size_t)WSZ, bd + 1 * GD, dinv, nullptr, dbuf2, hs_bf, nullptr, nullptr);
    k_spmm<<<GN / 4, 256, 0, stream>>>((const u32x2*)hs_bf, col, cnt, dinv, (u32x2*)y_bf);
    k_gemm<<<ggrid, 256, 0, stream>>>(y_bf, w_bf + 2 * (size_t)WSZ, bd + 2 * GD, dinv, nullptr, dbuf3, hs_bf, nullptr, nullptr);

    // bottom: hs_out with skip = down_outs[2]
    k_spmm<<<GN / 4, 256, 0, stream>>>((const u32x2*)hs_bf, col, cnt, dinv, (u32x2*)y_bf);
    k_gemm<<<ggrid, 256, 0, stream>>>(y_bf, w_bf + 3 * (size_t)WSZ, bb, dinv, dbuf3, nullptr, hs_bf, nullptr, nullptr);

    // up 0: out[0] = h5; next hs with skip = down_outs[1]
    k_spmm<<<GN / 4, 256, 0, stream>>>((const u32x2*)hs_bf, col, cnt, dinv, (u32x2*)y_bf);
    k_gemm<<<ggrid, 256, 0, stream>>>(y_bf, w_bf + 4 * (size_t)WSZ, bu + 0 * GD, dinv, dbuf2, out + 0 * ND, hs_bf, nullptr, nullptr);
    // up 1: out[1] = h6; next hs with skip = down_outs[0]
    k_spmm<<<GN / 4, 256, 0, stream>>>((const u32x2*)hs_bf, col, cnt, dinv, (u32x2*)y_bf);
    k_gemm<<<ggrid, 256, 0, stream>>>(y_bf, w_bf + 5 * (size_t)WSZ, bu + 1 * GD, dinv, dbuf1, out + 1 * ND, hs_bf, nullptr, nullptr);
    // up 2: out[2] = h7; out[3] = h7 + org_h
    k_spmm<<<GN / 4, 256, 0, stream>>>((const u32x2*)hs_bf, col, cnt, dinv, (u32x2*)y_bf);
    k_gemm<<<ggrid, 256, 0, stream>>>(y_bf, w_bf + 6 * (size_t)WSZ, bu + 2 * GD, dinv, nullptr, out + 2 * ND, nullptr, out + 3 * ND, h);
}